// Round 3
// baseline (293.978 us; speedup 1.0000x reference)
//
#include <hip/hip_runtime.h>
#include <stdint.h>

#define N_TOK 32768
#define D_IN  1024
#define U_OUT 1024

typedef __attribute__((ext_vector_type(4))) int int32x4;

__device__ __forceinline__ void async_copy16(const void* g, void* l) {
  __builtin_amdgcn_global_load_lds(
      (const __attribute__((address_space(1))) void*)g,
      (__attribute__((address_space(3))) void*)l,
      16, 0, 0);
}

// ---------------------------------------------------------------------------
// Kernel 1: per-row sign quantization (int8 +-1) + beta = mean(|x|) per row.
// One wave per row; per-instruction coalesced float4 loads (lane-contiguous),
// packed 4B sign stores.
// ---------------------------------------------------------------------------
__global__ __launch_bounds__(256) void quant_kernel(
    const float* __restrict__ x,
    char* __restrict__ xq,            // i8 {+1,-1} [N_TOK][D_IN]
    float* __restrict__ beta) {
  const int wave = threadIdx.x >> 6;
  const int lane = threadIdx.x & 63;
  const int row  = blockIdx.x * 4 + wave;

  const float4* p = (const float4*)(x + (size_t)row * D_IN);
  uint32_t* outw = (uint32_t*)(xq + (size_t)row * D_IN);
  float asum = 0.f;
  #pragma unroll
  for (int j = 0; j < 4; ++j) {
    const float4 v = p[j * 64 + lane];               // 1 KiB contiguous/instr
    asum += fabsf(v.x) + fabsf(v.y) + fabsf(v.z) + fabsf(v.w);
    uint32_t w =  (uint32_t)(uint8_t)(char)(v.x >= 0.f ? 1 : -1)
               | ((uint32_t)(uint8_t)(char)(v.y >= 0.f ? 1 : -1) << 8)
               | ((uint32_t)(uint8_t)(char)(v.z >= 0.f ? 1 : -1) << 16)
               | ((uint32_t)(uint8_t)(char)(v.w >= 0.f ? 1 : -1) << 24);
    outw[j * 64 + lane] = w;                         // 256 B contiguous/instr
  }
  #pragma unroll
  for (int off = 32; off > 0; off >>= 1)
    asum += __shfl_down(asum, off, 64);
  if (lane == 0) beta[row] = asum * (1.0f / (float)D_IN);
}

// ---------------------------------------------------------------------------
// Kernel 2 (unchanged): W[d,u] = sum_e a_e[u]*sign(k_e[d,u]) quantized to i8
// with exact per-column scale q[u] = (a0+a1+a2)/127.
// ---------------------------------------------------------------------------
__global__ __launch_bounds__(256) void wt_kernel(
    const float* __restrict__ k0, const float* __restrict__ k1,
    const float* __restrict__ k2,
    const float* __restrict__ a0, const float* __restrict__ a1,
    const float* __restrict__ a2,
    char* __restrict__ wt,            // i8 [U_OUT][D_IN]
    float* __restrict__ q) {          // f32 [U_OUT]
  const int tid = threadIdx.x;
  const int d0  = blockIdx.x * 16;
  const int u0  = tid * 4;

  const float4 av0 = *(const float4*)(a0 + u0);
  const float4 av1 = *(const float4*)(a1 + u0);
  const float4 av2 = *(const float4*)(a2 + u0);
  float4 s;
  s.x = fmaxf(av0.x + av1.x + av2.x, 1e-20f);
  s.y = fmaxf(av0.y + av1.y + av2.y, 1e-20f);
  s.z = fmaxf(av0.z + av1.z + av2.z, 1e-20f);
  s.w = fmaxf(av0.w + av1.w + av2.w, 1e-20f);
  if (blockIdx.x == 0) {
    float4 qv;
    qv.x = s.x * (1.0f / 127.0f); qv.y = s.y * (1.0f / 127.0f);
    qv.z = s.z * (1.0f / 127.0f); qv.w = s.w * (1.0f / 127.0f);
    *(float4*)(q + u0) = qv;
  }
  const float4 inv = {127.0f / s.x, 127.0f / s.y, 127.0f / s.z, 127.0f / s.w};

  alignas(16) char buf[4][16];
  #pragma unroll
  for (int d = 0; d < 16; ++d) {
    const size_t off = (size_t)(d0 + d) * U_OUT + u0;
    const float4 v0 = *(const float4*)(k0 + off);
    const float4 v1 = *(const float4*)(k1 + off);
    const float4 v2 = *(const float4*)(k2 + off);
    float4 w;
    w.x = (v0.x >= 0.f ? av0.x : -av0.x) + (v1.x >= 0.f ? av1.x : -av1.x)
        + (v2.x >= 0.f ? av2.x : -av2.x);
    w.y = (v0.y >= 0.f ? av0.y : -av0.y) + (v1.y >= 0.f ? av1.y : -av1.y)
        + (v2.y >= 0.f ? av2.y : -av2.y);
    w.z = (v0.z >= 0.f ? av0.z : -av0.z) + (v1.z >= 0.f ? av1.z : -av1.z)
        + (v2.z >= 0.f ? av2.z : -av2.z);
    w.w = (v0.w >= 0.f ? av0.w : -av0.w) + (v1.w >= 0.f ? av1.w : -av1.w)
        + (v2.w >= 0.f ? av2.w : -av2.w);
    buf[0][d] = (char)(int)rintf(w.x * inv.x);
    buf[1][d] = (char)(int)rintf(w.y * inv.y);
    buf[2][d] = (char)(int)rintf(w.z * inv.z);
    buf[3][d] = (char)(int)rintf(w.w * inv.w);
  }
  #pragma unroll
  for (int j = 0; j < 4; ++j)
    *(int32x4*)(wt + (size_t)(u0 + j) * D_IN + d0) = *(const int32x4*)buf[j];
}

// ---------------------------------------------------------------------------
// Kernel 3: C[n,u] = beta[n]*q[u] * (Xq[n,:] . Wt[u,:])  -- i8 MFMA GEMM.
// 256x256 tile, BK=64 i8 (64 B rows), 8 waves (2Mx4N), 512 threads.
// Phased schedule (T3+T4): 2 phases/tile, 3-deep LDS tile rotation so the
// tile-boundary wait is a COUNTED vmcnt(4) (tile T+2's loads stay in flight;
// never drains mid-loop). T2 XOR swizzle (both-sides: pre-swizzled global
// source col for global_load_lds, same XOR on ds_read). T5 setprio around
// each 16-MFMA cluster. XCD-aware block swizzle (512 blocks, 512%8==0).
// Hang-audited: uniform control flow (all barriers reached by all waves),
// waitcnt counts balance at every boundary, all addresses exact-fit.
// Integer accumulation order identical to round-0 kernel -> same output.
// ---------------------------------------------------------------------------
#define BM 256
#define BN 256
#define BKT 64
#define NKT (D_IN / BKT)   // 16

__global__ __launch_bounds__(512, 2) void gemm_kernel(
    const char* __restrict__ A,       // [M,K] i8
    const char* __restrict__ Bt,      // [N,K] i8
    const float* __restrict__ beta,
    const float* __restrict__ q,
    float* __restrict__ C) {
  __shared__ char As[3][BM * BKT];    // 3 x 16 KiB
  __shared__ char Bs[3][BN * BKT];    // 3 x 16 KiB  (96 KiB total)

  const int bid = blockIdx.x;
  const int xcd = bid & 7;
  const int g   = bid >> 3;                   // 0..63
  const int m0  = (xcd * 16 + (g >> 2)) * BM; // 16 m-tiles per XCD band
  const int n0  = (g & 3) * BN;

  const int tid  = threadIdx.x;
  const int wave = tid >> 6;
  const int lane = tid & 63;
  const int wr   = wave >> 2;          // 0..1 (M)
  const int wc   = wave & 3;           // 0..3 (N)
  const int lrow = lane & 15;
  const int quad = lane >> 4;

  // staging: thread covers LDS linear slot tid*16 (chunk j adds 8192);
  // LDS[row][c] holds G[row][c ^ ((row&3)<<4)]  (row = j*128 + tid>>2)
  const int srow = tid >> 2;                          // 0..127
  const int scol = (((tid & 3) ^ (srow & 3)) << 4);   // pre-swizzled col
  const char* gA0 = A  + (size_t)(m0 +       srow) * D_IN + scol;
  const char* gA1 = A  + (size_t)(m0 + 128 + srow) * D_IN + scol;
  const char* gB0 = Bt + (size_t)(n0 +       srow) * D_IN + scol;
  const char* gB1 = Bt + (size_t)(n0 + 128 + srow) * D_IN + scol;
  const int ldst = tid * 16;

  // frag reads: row = (wave band) + i*16 + lrow; want global k-col quad*16,
  // stored at c = (quad*16) ^ ((row&3)<<4), and row&3 == lane&3.
  const int rdcol = ((quad ^ (lane & 3)) << 4);

  int32x4 acc[8][4] = {};

  // prologue: stage tiles 0 and 1 (8 loads/thread), keep tile 1 in flight
  async_copy16(gA0,        As[0] + ldst);
  async_copy16(gA1,        As[0] + 8192 + ldst);
  async_copy16(gB0,        Bs[0] + ldst);
  async_copy16(gB1,        Bs[0] + 8192 + ldst);
  async_copy16(gA0 + BKT,  As[1] + ldst);
  async_copy16(gA1 + BKT,  As[1] + 8192 + ldst);
  async_copy16(gB0 + BKT,  Bs[1] + ldst);
  async_copy16(gB1 + BKT,  Bs[1] + 8192 + ldst);
  asm volatile("s_waitcnt vmcnt(4)" ::: "memory");
  __builtin_amdgcn_s_barrier();

  int p = 0;
  for (int T = 0; T < NKT; ++T) {
    const char* Ap = As[p];
    const char* Bp = Bs[p];
    int pn = p + 2; if (pn >= 3) pn -= 3;     // buffer for tile T+2
    const bool st = (T + 2 < NKT);
    const int kt2 = (T + 2) * BKT;

    // ---- phase 0: mi 0..3 x ni 0..3 ----
    int32x4 af[4], bf[4];
    #pragma unroll
    for (int i = 0; i < 4; ++i) {
      af[i] = *(const int32x4*)(Ap + (wr * 128 + i * 16 + lrow) * BKT + rdcol);
      bf[i] = *(const int32x4*)(Bp + (wc * 64  + i * 16 + lrow) * BKT + rdcol);
    }
    if (st) {
      async_copy16(gA0 + kt2, As[pn] + ldst);
      async_copy16(gA1 + kt2, As[pn] + 8192 + ldst);
    }
    __builtin_amdgcn_s_barrier();
    __builtin_amdgcn_s_setprio(1);
    #pragma unroll
    for (int mi = 0; mi < 4; ++mi)
      #pragma unroll
      for (int ni = 0; ni < 4; ++ni)
        acc[mi][ni] = __builtin_amdgcn_mfma_i32_16x16x64_i8(
            af[mi], bf[ni], acc[mi][ni], 0, 0, 0);
    __builtin_amdgcn_s_setprio(0);
    __builtin_amdgcn_s_barrier();

    // ---- phase 1: mi 4..7 x ni 0..3 (bf reused) ----
    int32x4 ag[4];
    #pragma unroll
    for (int i = 0; i < 4; ++i)
      ag[i] = *(const int32x4*)(Ap + (wr * 128 + (i + 4) * 16 + lrow) * BKT + rdcol);
    if (st) {
      async_copy16(gB0 + kt2, Bs[pn] + ldst);
      async_copy16(gB1 + kt2, Bs[pn] + 8192 + ldst);
    }
    __builtin_amdgcn_s_barrier();
    __builtin_amdgcn_s_setprio(1);
    #pragma unroll
    for (int mi = 0; mi < 4; ++mi)
      #pragma unroll
      for (int ni = 0; ni < 4; ++ni)
        acc[mi + 4][ni] = __builtin_amdgcn_mfma_i32_16x16x64_i8(
            ag[mi], bf[ni], acc[mi + 4][ni], 0, 0, 0);
    __builtin_amdgcn_s_setprio(0);

    // tile-boundary wait: tile T+1 must be resident; tile T+2 stays in flight
    if (T < NKT - 2) {
      asm volatile("s_waitcnt vmcnt(4)" ::: "memory");
    } else if (T == NKT - 2) {
      asm volatile("s_waitcnt vmcnt(0)" ::: "memory");
    }
    __builtin_amdgcn_s_barrier();

    p = p + 1; if (p >= 3) p -= 3;
  }

  // epilogue: C/D layout col=lane&15, row=quad*4+reg (dtype-independent)
  float qv[4];
  #pragma unroll
  for (int ni = 0; ni < 4; ++ni)
    qv[ni] = q[n0 + wc * 64 + ni * 16 + lrow];
  #pragma unroll
  for (int mi = 0; mi < 8; ++mi) {
    #pragma unroll
    for (int r = 0; r < 4; ++r) {
      const int row = m0 + wr * 128 + mi * 16 + quad * 4 + r;
      const float b = beta[row];
      #pragma unroll
      for (int ni = 0; ni < 4; ++ni) {
        const int col = n0 + wc * 64 + ni * 16 + lrow;
        C[(size_t)row * U_OUT + col] = (float)acc[mi][ni][r] * b * qv[ni];
      }
    }
  }
}

// ---------------------------------------------------------------------------
extern "C" void kernel_launch(void* const* d_in, const int* in_sizes, int n_in,
                              void* d_out, int out_size, void* d_ws, size_t ws_size,
                              hipStream_t stream) {
  const float* x  = (const float*)d_in[0];
  const float* k0 = (const float*)d_in[1];
  const float* k1 = (const float*)d_in[2];
  const float* k2 = (const float*)d_in[3];
  const float* a0 = (const float*)d_in[4];
  const float* a1 = (const float*)d_in[5];
  const float* a2 = (const float*)d_in[6];
  float* out = (float*)d_out;

  char* ws = (char*)d_ws;
  char*  xq   = ws;                                          // 32 MiB
  char*  wt   = ws + (size_t)N_TOK * D_IN;                   // 1 MiB
  float* q    = (float*)(wt + (size_t)U_OUT * D_IN);         // 4 KiB
  float* beta = q + U_OUT;                                   // 128 KiB

  quant_kernel<<<N_TOK / 4, 256, 0, stream>>>(x, xq, beta);
  wt_kernel<<<64, 256, 0, stream>>>(k0, k1, k2, a0, a1, a2, wt, q);
  gemm_kernel<<<(N_TOK / BM) * (U_OUT / BN), 512, 0, stream>>>(xq, wt, beta, q, out);
}